// Round 5
// baseline (244.651 us; speedup 1.0000x reference)
//
#include <hip/hip_runtime.h>

typedef __attribute__((ext_vector_type(8))) short bf16x8;
typedef __attribute__((ext_vector_type(4))) float f32x4;
typedef __attribute__((ext_vector_type(16))) float f32x16;
typedef unsigned short u16;
typedef unsigned int u32;
typedef __attribute__((ext_vector_type(4))) unsigned int u32x4;

#define DEV static __device__ __forceinline__

DEV u16 f2bf(float f) {
  u32 u = __float_as_uint(f);
  u += 0x7FFFu + ((u >> 16) & 1u);
  return (u16)(u >> 16);
}
DEV float bf2f(u16 h) { return __uint_as_float(((u32)h) << 16); }

DEV void gload16(const void* g, void* l) {
  __builtin_amdgcn_global_load_lds((const __attribute__((address_space(1))) void*)g,
                                   (__attribute__((address_space(3))) void*)l, 16, 0, 0);
}

#define MFMA16(a, b, c) __builtin_amdgcn_mfma_f32_16x16x32_bf16((a), (b), (c), 0, 0, 0)
#define MFMA32(a, b, c) __builtin_amdgcn_mfma_f32_32x32x16_bf16((a), (b), (c), 0, 0, 0)

DEV u32 cvtpk(float lo, float hi) {
  u32 r;
  asm("v_cvt_pk_bf16_f32 %0, %1, %2" : "=v"(r) : "v"(lo), "v"(hi));
  return r;
}
DEV void plswap(u32& a, u32& b) {
  asm volatile("v_permlane32_swap_b32 %0, %1" : "+v"(a), "+v"(b));
}
DEV bf16x8 asbf(u32x4 v) {
  union { u32x4 u; bf16x8 b; } x;
  x.u = v;
  return x.b;
}

// ---------------- fp32 -> bf16 convert (x) ----------------
__global__ __launch_bounds__(256) void k_cvt_bf16(const float* __restrict__ in,
                                                  u16* __restrict__ out, int n8) {
  int i = blockIdx.x * 256 + threadIdx.x;
  if (i >= n8) return;
  const f32x4* p = (const f32x4*)(in + (size_t)i * 8);
  f32x4 a = p[0], b = p[1];
  bf16x8 o;
  o[0] = (short)f2bf(a[0]); o[1] = (short)f2bf(a[1]);
  o[2] = (short)f2bf(a[2]); o[3] = (short)f2bf(a[3]);
  o[4] = (short)f2bf(b[0]); o[5] = (short)f2bf(b[1]);
  o[6] = (short)f2bf(b[2]); o[7] = (short)f2bf(b[3]);
  *(bf16x8*)(out + (size_t)i * 8) = o;
}

// ---------------- fp32 [rows][cols] -> bf16 [cols][rows] ----------------
__global__ __launch_bounds__(256) void k_transpose_bf16(const float* __restrict__ src,
                                                        u16* __restrict__ dst,
                                                        int rows, int cols) {
  __shared__ u16 lds[64][72];
  int t = threadIdx.x;
  int r0 = blockIdx.y * 64, c0 = blockIdx.x * 64;
  int r = t >> 2, cq = (t & 3) << 4;
  const float* s = src + (size_t)(r0 + r) * cols + c0 + cq;
#pragma unroll
  for (int i = 0; i < 16; i += 4) {
    f32x4 v = *(const f32x4*)(s + i);
    lds[r][cq + i + 0] = f2bf(v[0]);
    lds[r][cq + i + 1] = f2bf(v[1]);
    lds[r][cq + i + 2] = f2bf(v[2]);
    lds[r][cq + i + 3] = f2bf(v[3]);
  }
  __syncthreads();
  int c = t >> 2, rq = (t & 3) << 4;
  bf16x8 o0, o1;
#pragma unroll
  for (int i = 0; i < 8; ++i) o0[i] = (short)lds[rq + i][c];
#pragma unroll
  for (int i = 0; i < 8; ++i) o1[i] = (short)lds[rq + 8 + i][c];
  u16* d = dst + (size_t)(c0 + c) * rows + r0 + rq;
  *(bf16x8*)d = o0;
  *(bf16x8*)(d + 8) = o1;
}

// ---------------- bf16 GEMM: C[M][N] = A[M][K] * Bt[N][K]^T ----------------
template <bool OUT_BF16, bool HAS_BIAS>
__global__ __launch_bounds__(256) void k_gemm_bt(const u16* __restrict__ A,
                                                 const u16* __restrict__ Bt,
                                                 void* __restrict__ Cout,
                                                 const float* __restrict__ bias,
                                                 int M, int N, int K) {
  __shared__ __align__(16) u16 lsA[128 * 32];
  __shared__ __align__(16) u16 lsB[128 * 32];
  int tid = threadIdx.x;
  int lane = tid & 63, wave = tid >> 6;
  int wr = (wave >> 1) * 64, wc = (wave & 1) * 64;
  int bm = blockIdx.y * 128, bn = blockIdx.x * 128;

  f32x4 acc[4][4] = {};

  const u16* aSrc[2]; u16* aDst[2];
  const u16* bSrc[2]; u16* bDst[2];
#pragma unroll
  for (int j = 0; j < 2; ++j) {
    int s = wave * 128 + j * 64 + lane;
    int row = s >> 2, chunk = s & 3;
    int g = chunk ^ ((row >> 1) & 3);
    aSrc[j] = A + (size_t)(bm + row) * K + g * 8;
    bSrc[j] = Bt + (size_t)(bn + row) * K + g * 8;
    aDst[j] = &lsA[(wave * 128 + j * 64) * 8];
    bDst[j] = &lsB[(wave * 128 + j * 64) * 8];
  }

  for (int k0 = 0; k0 < K; k0 += 32) {
    __syncthreads();
    gload16(aSrc[0] + k0, aDst[0]);
    gload16(aSrc[1] + k0, aDst[1]);
    gload16(bSrc[0] + k0, bDst[0]);
    gload16(bSrc[1] + k0, bDst[1]);
    __syncthreads();
    bf16x8 af[4], bfr[4];
#pragma unroll
    for (int m = 0; m < 4; ++m) {
      int r = wr + m * 16 + (lane & 15);
      int p = (lane >> 4) ^ ((r >> 1) & 3);
      af[m] = *(const bf16x8*)&lsA[r * 32 + p * 8];
    }
#pragma unroll
    for (int n = 0; n < 4; ++n) {
      int r = wc + n * 16 + (lane & 15);
      int p = (lane >> 4) ^ ((r >> 1) & 3);
      bfr[n] = *(const bf16x8*)&lsB[r * 32 + p * 8];
    }
#pragma unroll
    for (int m = 0; m < 4; ++m)
#pragma unroll
      for (int n = 0; n < 4; ++n)
        acc[m][n] = MFMA16(af[m], bfr[n], acc[m][n]);
  }

#pragma unroll
  for (int m = 0; m < 4; ++m) {
    int row = bm + wr + m * 16 + ((lane >> 4) << 2);
#pragma unroll
    for (int n = 0; n < 4; ++n) {
      int col = bn + wc + n * 16 + (lane & 15);
#pragma unroll
      for (int j = 0; j < 4; ++j) {
        if (OUT_BF16) {
          ((u16*)Cout)[(size_t)(row + j) * N + col] = f2bf(acc[m][n][j]);
        } else {
          float bb = HAS_BIAS ? bias[col] : 0.f;
          ((float*)Cout)[(size_t)(row + j) * N + col] = acc[m][n][j] + bb;
        }
      }
    }
  }
}

// ---------------- repack: normalize q,k (fold scale into q), transpose v ----------------
__global__ __launch_bounds__(256) void k_repack(const u16* __restrict__ QKV,
                                                const float* __restrict__ logit_scale,
                                                u16* __restrict__ Qn, u16* __restrict__ Kn,
                                                u16* __restrict__ Vt) {
  int nt = blockIdx.x;  // 0..31 (64-row tile)
  int h = blockIdx.y;   // 0..15
  int b = blockIdx.z;   // 0..1
  int tid = threadIdx.x;
  int lane = tid & 63, wave = tid >> 6;
  int bh = b * 16 + h;
  float scale = __expf(fminf(logit_scale[h], 4.6051701859880914f));

#pragma unroll 1
  for (int i = 0; i < 16; ++i) {
    int n = nt * 64 + wave * 16 + i;
    size_t off = ((size_t)(b * 2048 + n)) * 3072 + h * 64 + lane;
    float q = bf2f(QKV[off]);
    float k = bf2f(QKV[off + 1024]);
    float sq = q * q, sk = k * k;
#pragma unroll
    for (int d = 1; d < 64; d <<= 1) {
      sq += __shfl_xor(sq, d, 64);
      sk += __shfl_xor(sk, d, 64);
    }
    float rq = scale / fmaxf(sqrtf(sq), 1e-12f);
    float rk = 1.0f / fmaxf(sqrtf(sk), 1e-12f);
    size_t o2 = ((size_t)bh * 2048 + n) * 64 + lane;
    Qn[o2] = f2bf(q * rq);
    Kn[o2] = f2bf(k * rk);
  }

  // V transpose via LDS
  __shared__ u16 lds[64][72];
  int r = tid >> 2, cq = (tid & 3) << 4;
  size_t voff = ((size_t)(b * 2048 + nt * 64 + r)) * 3072 + 2048 + h * 64 + cq;
  *(bf16x8*)&lds[r][cq] = *(const bf16x8*)&QKV[voff];
  *(bf16x8*)&lds[r][cq + 8] = *(const bf16x8*)&QKV[voff + 8];
  __syncthreads();
  int d = tid >> 2, nq = (tid & 3) << 4;
  bf16x8 o0, o1;
#pragma unroll
  for (int i = 0; i < 8; ++i) o0[i] = (short)lds[nq + i][d];
#pragma unroll
  for (int i = 0; i < 8; ++i) o1[i] = (short)lds[nq + 8 + i][d];
  u16* vd = Vt + ((size_t)bh * 64 + d) * 2048 + nt * 64 + nq;
  *(bf16x8*)vd = o0;
  *(bf16x8*)(vd + 8) = o1;
}

// ---------------- flash attention (swapped-QK^T, fixed-max softmax, split-KV x2) ----------------
// K/V are L2-resident (R4: FETCH 12MB vs 30MB logical) -> load MFMA fragments DIRECTLY
// from global into registers. No LDS staging, no __syncthreads in the loop; waves fully
// independent, latency hidden by TLP. grid: (bh=32, qblk=16, split=2); blockIdx.x = bh
// keeps all blocks of a head on one XCD.
__global__ __launch_bounds__(256, 3) void k_flash(const u16* __restrict__ Qn,
                                                  const u16* __restrict__ Kn,
                                                  const u16* __restrict__ Vt,
                                                  const float* __restrict__ logit_scale,
                                                  u16* __restrict__ Op,
                                                  float* __restrict__ Lp) {
  __shared__ float l_s[4][32];
  int tid = threadIdx.x, lane = tid & 63, wave = tid >> 6;
  int r31 = lane & 31, h = lane >> 5;
  int bh = blockIdx.x, hd = bh & 15;
  int qw = blockIdx.y * 128 + wave * 32;
  int sp = blockIdx.z;
  const u16* Q = Qn + (size_t)bh * 2048 * 64;
  const u16* Kb = Kn + (size_t)bh * 2048 * 64 + (size_t)sp * 1024 * 64;
  const u16* Vb = Vt + (size_t)bh * 64 * 2048 + (size_t)sp * 1024;

  float negC = -__expf(fminf(logit_scale[hd], 4.6051701859880914f));

  // Q B-fragments: col=lane&31=q, k(d) = 16*ks + 8*h + e
  bf16x8 qB[4];
#pragma unroll
  for (int ks = 0; ks < 4; ++ks)
    qB[ks] = *(const bf16x8*)&Q[(size_t)(qw + r31) * 64 + ks * 16 + h * 8];

  // per-lane fragment bases
  // K frag (a,ks) at tile kv0: Kb[(kv0 + a*32 + r31)*64 + 16*ks + 8*h]  (16B load)
  // V frag (a,ks) at tile kv0: Vb[(a*32 + r31)*2048 + kv0 + 16*ks + 8*h]
  const u16* kBase[2];
  const u16* vBase[2];
#pragma unroll
  for (int a = 0; a < 2; ++a) {
    kBase[a] = Kb + (size_t)(a * 32 + r31) * 64 + h * 8;
    vBase[a] = Vb + (size_t)(a * 32 + r31) * 2048 + h * 8;
  }

  f32x16 o0, o1;
#pragma unroll
  for (int i = 0; i < 16; ++i) { o0[i] = 0.f; o1[i] = 0.f; }
  float lsum = 0.f;

#pragma unroll 1
  for (int t = 0; t < 16; ++t) {
    int kv0 = t * 64;

    // K fragments (registers, direct from L2)
    bf16x8 kf0[4], kf1[4];
#pragma unroll
    for (int ks = 0; ks < 4; ++ks) {
      kf0[ks] = *(const bf16x8*)(kBase[0] + (size_t)kv0 * 64 + ks * 16);
      kf1[ks] = *(const bf16x8*)(kBase[1] + (size_t)kv0 * 64 + ks * 16);
    }

    // S^T = K Q^T - scale   (rows kv, cols q)
    f32x16 s0, s1;
#pragma unroll
    for (int i = 0; i < 16; ++i) { s0[i] = negC; s1[i] = negC; }
#pragma unroll
    for (int ks = 0; ks < 4; ++ks) {
      s0 = MFMA32(kf0[ks], qB[ks], s0);
      s1 = MFMA32(kf1[ks], qB[ks], s1);
    }

    // V fragments: issue now so L2 latency hides under exp/pack
    bf16x8 vf0[4], vf1[4];
#pragma unroll
    for (int ks = 0; ks < 4; ++ks) {
      vf0[ks] = *(const bf16x8*)(vBase[0] + kv0 + ks * 16);
      vf1[ks] = *(const bf16x8*)(vBase[1] + kv0 + ks * 16);
    }

    // P = exp(S - scale), lane-local l accumulation (no max, no shuffles)
#pragma unroll
    for (int i = 0; i < 16; ++i) {
      float e0 = __expf(s0[i]);
      float e1 = __expf(s1[i]);
      lsum += e0 + e1;
      s0[i] = e0; s1[i] = e1;
    }

    // pack P rows into PV A-fragments: cvt_pk pairs + permlane32 half-swap
    bf16x8 pa[4];
    {
      u32 c0 = cvtpk(s0[0], s0[1]),  c1 = cvtpk(s0[2], s0[3]);
      u32 c2 = cvtpk(s0[4], s0[5]),  c3 = cvtpk(s0[6], s0[7]);
      u32 c4 = cvtpk(s0[8], s0[9]),  c5 = cvtpk(s0[10], s0[11]);
      u32 c6 = cvtpk(s0[12], s0[13]), c7 = cvtpk(s0[14], s0[15]);
      plswap(c0, c2); plswap(c1, c3); plswap(c4, c6); plswap(c5, c7);
      pa[0] = asbf((u32x4){c0, c1, c2, c3});
      pa[1] = asbf((u32x4){c4, c5, c6, c7});
      u32 d0 = cvtpk(s1[0], s1[1]),  d1 = cvtpk(s1[2], s1[3]);
      u32 d2 = cvtpk(s1[4], s1[5]),  d3 = cvtpk(s1[6], s1[7]);
      u32 d4 = cvtpk(s1[8], s1[9]),  d5 = cvtpk(s1[10], s1[11]);
      u32 d6 = cvtpk(s1[12], s1[13]), d7 = cvtpk(s1[14], s1[15]);
      plswap(d0, d2); plswap(d1, d3); plswap(d4, d6); plswap(d5, d7);
      pa[2] = asbf((u32x4){d0, d1, d2, d3});
      pa[3] = asbf((u32x4){d4, d5, d6, d7});
    }

    // O += P V
#pragma unroll
    for (int ks = 0; ks < 4; ++ks) {
      o0 = MFMA32(pa[ks], vf0[ks], o0);
      o1 = MFMA32(pa[ks], vf1[ks], o1);
    }
  }

  // combine l across lane halves; stash per-split l; redistribute 1/l via LDS
  float ltot = lsum + __shfl_xor(lsum, 32, 64);
  if (h == 0) {
    l_s[wave][r31] = 1.0f / ltot;
    Lp[((size_t)sp * 32 + bh) * 2048 + qw + r31] = ltot;
  }
  __syncthreads();

#pragma unroll
  for (int r = 0; r < 16; ++r) {
    int cr = (r & 3) + ((r >> 2) << 3) + (h << 2);
    int qr = qw + cr;
    float li = l_s[wave][cr];
    size_t base = (((size_t)sp * 32 + bh) * 2048 + qr) * 64;
    Op[base + r31] = f2bf(o0[r] * li);
    Op[base + 32 + r31] = f2bf(o1[r] * li);
  }
}

// ---------------- combine split-KV partials -> AO[b*2048+n][h*64+d] ----------------
__global__ __launch_bounds__(256) void k_combine(const u16* __restrict__ Op,
                                                 const float* __restrict__ Lp,
                                                 u16* __restrict__ AO) {
  int idx = blockIdx.x * 256 + threadIdx.x;  // 524288 groups of 8
  int row = idx >> 3;                        // bh*2048 + n
  int d0 = (idx & 7) << 3;
  float l1 = Lp[row], l2 = Lp[65536 + row];
  float inv = 1.0f / (l1 + l2);
  float w1 = l1 * inv, w2 = l2 * inv;
  bf16x8 a = *(const bf16x8*)&Op[(size_t)row * 64 + d0];
  bf16x8 b = *(const bf16x8*)&Op[4194304 + (size_t)row * 64 + d0];
  int bh = row >> 11, n = row & 2047;
  int bb = bh >> 4, hd = bh & 15;
  bf16x8 o;
#pragma unroll
  for (int e = 0; e < 8; ++e)
    o[e] = (short)f2bf(w1 * bf2f(a[e]) + w2 * bf2f(b[e]));
  *(bf16x8*)&AO[((size_t)(bb * 2048 + n)) * 1024 + hd * 64 + d0] = o;
}

// ---------------- host ----------------
extern "C" void kernel_launch(void* const* d_in, const int* in_sizes, int n_in,
                              void* d_out, int out_size, void* d_ws, size_t ws_size,
                              hipStream_t stream) {
  const float* x = (const float*)d_in[0];
  const float* w_qkv = (const float*)d_in[1];
  const float* w_out = (const float*)d_in[2];
  const float* b_out = (const float*)d_in[3];
  const float* logit_scale = (const float*)d_in[4];

  char* ws = (char*)d_ws;
  u16* Xbf   = (u16*)(ws);                   // 8 MB  [4096][1024]
  u16* Wqkvt = (u16*)(ws + (8ll << 20));     // 6 MB  [3072][1024] (reused as Lp after gemm1)
  u16* Woutt = (u16*)(ws + (14ll << 20));    // 2 MB  [1024][1024]
  u16* QKV   = (u16*)(ws + (16ll << 20));    // 24 MB [4096][3072] (reused as Op after repack)
  u16* Qn    = (u16*)(ws + (40ll << 20));    // 8 MB  [2][16][2048][64]
  u16* Kn    = (u16*)(ws + (48ll << 20));    // 8 MB
  u16* Vt    = (u16*)(ws + (56ll << 20));    // 8 MB  [2][16][64][2048]
  u16* Op    = QKV;                          // 16 MB [2][32][2048][64] bf16
  float* Lp  = (float*)Wqkvt;                // 0.5 MB [2][32][2048] f32
  u16* AO    = Xbf;                          // reuse x-bf16 region [4096][1024]
  float* out = (float*)d_out;

  k_cvt_bf16<<<2048, 256, 0, stream>>>(x, Xbf, 524288);
  k_transpose_bf16<<<dim3(48, 16), 256, 0, stream>>>(w_qkv, Wqkvt, 1024, 3072);
  k_transpose_bf16<<<dim3(16, 16), 256, 0, stream>>>(w_out, Woutt, 1024, 1024);
  k_gemm_bt<true, false><<<dim3(24, 32), 256, 0, stream>>>(Xbf, Wqkvt, QKV, nullptr,
                                                           4096, 3072, 1024);
  k_repack<<<dim3(32, 16, 2), 256, 0, stream>>>(QKV, logit_scale, Qn, Kn, Vt);
  k_flash<<<dim3(32, 16, 2), 256, 0, stream>>>(Qn, Kn, Vt, logit_scale, Op, Lp);
  k_combine<<<2048, 256, 0, stream>>>(Op, Lp, AO);
  k_gemm_bt<false, true><<<dim3(8, 32), 256, 0, stream>>>(AO, Woutt, out, b_out,
                                                          4096, 1024, 1024);
}

// Round 6
// 213.155 us; speedup vs baseline: 1.1478x; 1.1478x over previous
//
#include <hip/hip_runtime.h>

typedef __attribute__((ext_vector_type(8))) short bf16x8;
typedef __attribute__((ext_vector_type(4))) float f32x4;
typedef __attribute__((ext_vector_type(16))) float f32x16;
typedef unsigned short u16;
typedef unsigned int u32;
typedef __attribute__((ext_vector_type(4))) unsigned int u32x4;

#define DEV static __device__ __forceinline__

DEV u16 f2bf(float f) {
  u32 u = __float_as_uint(f);
  u += 0x7FFFu + ((u >> 16) & 1u);
  return (u16)(u >> 16);
}
DEV float bf2f(u16 h) { return __uint_as_float(((u32)h) << 16); }

DEV void gload16(const void* g, void* l) {
  __builtin_amdgcn_global_load_lds((const __attribute__((address_space(1))) void*)g,
                                   (__attribute__((address_space(3))) void*)l, 16, 0, 0);
}

#define MFMA16(a, b, c) __builtin_amdgcn_mfma_f32_16x16x32_bf16((a), (b), (c), 0, 0, 0)
#define MFMA32(a, b, c) __builtin_amdgcn_mfma_f32_32x32x16_bf16((a), (b), (c), 0, 0, 0)

DEV u32 cvtpk(float lo, float hi) {
  u32 r;
  asm("v_cvt_pk_bf16_f32 %0, %1, %2" : "=v"(r) : "v"(lo), "v"(hi));
  return r;
}
DEV void plswap(u32& a, u32& b) {
  asm volatile("v_permlane32_swap_b32 %0, %1" : "+v"(a), "+v"(b));
}
DEV bf16x8 asbf(u32x4 v) {
  union { u32x4 u; bf16x8 b; } x;
  x.u = v;
  return x.b;
}

// ---------------- fp32 -> bf16 convert (x) ----------------
__global__ __launch_bounds__(256) void k_cvt_bf16(const float* __restrict__ in,
                                                  u16* __restrict__ out, int n8) {
  int i = blockIdx.x * 256 + threadIdx.x;
  if (i >= n8) return;
  const f32x4* p = (const f32x4*)(in + (size_t)i * 8);
  f32x4 a = p[0], b = p[1];
  bf16x8 o;
  o[0] = (short)f2bf(a[0]); o[1] = (short)f2bf(a[1]);
  o[2] = (short)f2bf(a[2]); o[3] = (short)f2bf(a[3]);
  o[4] = (short)f2bf(b[0]); o[5] = (short)f2bf(b[1]);
  o[6] = (short)f2bf(b[2]); o[7] = (short)f2bf(b[3]);
  *(bf16x8*)(out + (size_t)i * 8) = o;
}

// ---------------- fp32 [rows][cols] -> bf16 [cols][rows] ----------------
__global__ __launch_bounds__(256) void k_transpose_bf16(const float* __restrict__ src,
                                                        u16* __restrict__ dst,
                                                        int rows, int cols) {
  __shared__ u16 lds[64][72];
  int t = threadIdx.x;
  int r0 = blockIdx.y * 64, c0 = blockIdx.x * 64;
  int r = t >> 2, cq = (t & 3) << 4;
  const float* s = src + (size_t)(r0 + r) * cols + c0 + cq;
#pragma unroll
  for (int i = 0; i < 16; i += 4) {
    f32x4 v = *(const f32x4*)(s + i);
    lds[r][cq + i + 0] = f2bf(v[0]);
    lds[r][cq + i + 1] = f2bf(v[1]);
    lds[r][cq + i + 2] = f2bf(v[2]);
    lds[r][cq + i + 3] = f2bf(v[3]);
  }
  __syncthreads();
  int c = t >> 2, rq = (t & 3) << 4;
  bf16x8 o0, o1;
#pragma unroll
  for (int i = 0; i < 8; ++i) o0[i] = (short)lds[rq + i][c];
#pragma unroll
  for (int i = 0; i < 8; ++i) o1[i] = (short)lds[rq + 8 + i][c];
  u16* d = dst + (size_t)(c0 + c) * rows + r0 + rq;
  *(bf16x8*)d = o0;
  *(bf16x8*)(d + 8) = o1;
}

// ---------------- bf16 GEMM: C[M][N] = A[M][K] * Bt[N][K]^T ----------------
// 1D grid with bijective XCD swizzle (nwg % 8 == 0): wg = (orig&7)*(nwg/8) + orig/8.
template <bool OUT_BF16, bool HAS_BIAS>
__global__ __launch_bounds__(256) void k_gemm_bt(const u16* __restrict__ A,
                                                 const u16* __restrict__ Bt,
                                                 void* __restrict__ Cout,
                                                 const float* __restrict__ bias,
                                                 int M, int N, int K, int nbx) {
  __shared__ __align__(16) u16 lsA[128 * 32];
  __shared__ __align__(16) u16 lsB[128 * 32];
  int tid = threadIdx.x;
  int lane = tid & 63, wave = tid >> 6;
  int wr = (wave >> 1) * 64, wc = (wave & 1) * 64;
  int nwg = gridDim.x;
  int orig = blockIdx.x;
  int wg = (orig & 7) * (nwg >> 3) + (orig >> 3);
  int bm = (wg / nbx) * 128, bn = (wg % nbx) * 128;

  f32x4 acc[4][4] = {};

  const u16* aSrc[2]; u16* aDst[2];
  const u16* bSrc[2]; u16* bDst[2];
#pragma unroll
  for (int j = 0; j < 2; ++j) {
    int s = wave * 128 + j * 64 + lane;
    int row = s >> 2, chunk = s & 3;
    int g = chunk ^ ((row >> 1) & 3);
    aSrc[j] = A + (size_t)(bm + row) * K + g * 8;
    bSrc[j] = Bt + (size_t)(bn + row) * K + g * 8;
    aDst[j] = &lsA[(wave * 128 + j * 64) * 8];
    bDst[j] = &lsB[(wave * 128 + j * 64) * 8];
  }

  for (int k0 = 0; k0 < K; k0 += 32) {
    __syncthreads();
    gload16(aSrc[0] + k0, aDst[0]);
    gload16(aSrc[1] + k0, aDst[1]);
    gload16(bSrc[0] + k0, bDst[0]);
    gload16(bSrc[1] + k0, bDst[1]);
    __syncthreads();
    bf16x8 af[4], bfr[4];
#pragma unroll
    for (int m = 0; m < 4; ++m) {
      int r = wr + m * 16 + (lane & 15);
      int p = (lane >> 4) ^ ((r >> 1) & 3);
      af[m] = *(const bf16x8*)&lsA[r * 32 + p * 8];
    }
#pragma unroll
    for (int n = 0; n < 4; ++n) {
      int r = wc + n * 16 + (lane & 15);
      int p = (lane >> 4) ^ ((r >> 1) & 3);
      bfr[n] = *(const bf16x8*)&lsB[r * 32 + p * 8];
    }
#pragma unroll
    for (int m = 0; m < 4; ++m)
#pragma unroll
      for (int n = 0; n < 4; ++n)
        acc[m][n] = MFMA16(af[m], bfr[n], acc[m][n]);
  }

#pragma unroll
  for (int m = 0; m < 4; ++m) {
    int row = bm + wr + m * 16 + ((lane >> 4) << 2);
#pragma unroll
    for (int n = 0; n < 4; ++n) {
      int col = bn + wc + n * 16 + (lane & 15);
#pragma unroll
      for (int j = 0; j < 4; ++j) {
        if (OUT_BF16) {
          ((u16*)Cout)[(size_t)(row + j) * N + col] = f2bf(acc[m][n][j]);
        } else {
          float bb = HAS_BIAS ? bias[col] : 0.f;
          ((float*)Cout)[(size_t)(row + j) * N + col] = acc[m][n][j] + bb;
        }
      }
    }
  }
}

// ---------------- repack: normalize q,k (fold scale into q), transpose v ----------------
__global__ __launch_bounds__(256) void k_repack(const u16* __restrict__ QKV,
                                                const float* __restrict__ logit_scale,
                                                u16* __restrict__ Qn, u16* __restrict__ Kn,
                                                u16* __restrict__ Vt) {
  int nt = blockIdx.x;  // 0..31 (64-row tile)
  int h = blockIdx.y;   // 0..15
  int b = blockIdx.z;   // 0..1
  int tid = threadIdx.x;
  int lane = tid & 63, wave = tid >> 6;
  int bh = b * 16 + h;
  float scale = __expf(fminf(logit_scale[h], 4.6051701859880914f));

#pragma unroll 1
  for (int i = 0; i < 16; ++i) {
    int n = nt * 64 + wave * 16 + i;
    size_t off = ((size_t)(b * 2048 + n)) * 3072 + h * 64 + lane;
    float q = bf2f(QKV[off]);
    float k = bf2f(QKV[off + 1024]);
    float sq = q * q, sk = k * k;
#pragma unroll
    for (int d = 1; d < 64; d <<= 1) {
      sq += __shfl_xor(sq, d, 64);
      sk += __shfl_xor(sk, d, 64);
    }
    float rq = scale / fmaxf(sqrtf(sq), 1e-12f);
    float rk = 1.0f / fmaxf(sqrtf(sk), 1e-12f);
    size_t o2 = ((size_t)bh * 2048 + n) * 64 + lane;
    Qn[o2] = f2bf(q * rq);
    Kn[o2] = f2bf(k * rk);
  }

  // V transpose via LDS
  __shared__ u16 lds[64][72];
  int r = tid >> 2, cq = (tid & 3) << 4;
  size_t voff = ((size_t)(b * 2048 + nt * 64 + r)) * 3072 + 2048 + h * 64 + cq;
  *(bf16x8*)&lds[r][cq] = *(const bf16x8*)&QKV[voff];
  *(bf16x8*)&lds[r][cq + 8] = *(const bf16x8*)&QKV[voff + 8];
  __syncthreads();
  int d = tid >> 2, nq = (tid & 3) << 4;
  bf16x8 o0, o1;
#pragma unroll
  for (int i = 0; i < 8; ++i) o0[i] = (short)lds[nq + i][d];
#pragma unroll
  for (int i = 0; i < 8; ++i) o1[i] = (short)lds[nq + 8 + i][d];
  u16* vd = Vt + ((size_t)bh * 64 + d) * 2048 + nt * 64 + nq;
  *(bf16x8*)vd = o0;
  *(bf16x8*)(vd + 8) = o1;
}

// ---------------- flash attention (register-pipelined, barrier-free) ----------------
// K/V are L2-resident. MFMA fragments load DIRECTLY to registers with an EXPLICIT
// K double-buffer: tile t+1's K is issued at iteration top (pinned by sched_barrier)
// and consumed next iteration; V is issued after the QK MFMAs and consumed after
// exp/pack (~400cy distance > L2 latency). No LDS staging, no __syncthreads in loop.
// grid (bh=32, qblk=16) = 512 blocks = 2 resident blocks/CU at 256 VGPR.
__global__ __launch_bounds__(256, 2) void k_flash(const u16* __restrict__ Qn,
                                                  const u16* __restrict__ Kn,
                                                  const u16* __restrict__ Vt,
                                                  const float* __restrict__ logit_scale,
                                                  u16* __restrict__ AO) {
  __shared__ float l_s[4][32];
  int tid = threadIdx.x, lane = tid & 63, wave = tid >> 6;
  int r31 = lane & 31, h = lane >> 5;
  int bh = blockIdx.x, b = bh >> 4, hd = bh & 15;
  int qw = blockIdx.y * 128 + wave * 32;
  const u16* Q = Qn + (size_t)bh * 2048 * 64;
  const u16* Kb = Kn + (size_t)bh * 2048 * 64;
  const u16* Vb = Vt + (size_t)bh * 64 * 2048;

  float negC = -__expf(fminf(logit_scale[hd], 4.6051701859880914f));

  // Q B-fragments: col=lane&31=q, k(d) = 16*ks + 8*h + e
  bf16x8 qB[4];
#pragma unroll
  for (int ks = 0; ks < 4; ++ks)
    qB[ks] = *(const bf16x8*)&Q[(size_t)(qw + r31) * 64 + ks * 16 + h * 8];

  // per-lane fragment bases
  const u16* kBase[2];
  const u16* vBase[2];
#pragma unroll
  for (int a = 0; a < 2; ++a) {
    kBase[a] = Kb + (size_t)(a * 32 + r31) * 64 + h * 8;
    vBase[a] = Vb + (size_t)(a * 32 + r31) * 2048 + h * 8;
  }

  f32x16 o0, o1;
#pragma unroll
  for (int i = 0; i < 16; ++i) { o0[i] = 0.f; o1[i] = 0.f; }
  float lsum = 0.f;

  bf16x8 kfA[8], kfB[8], vf[8];

  // prologue: K fragments for tile 0 into kfA
#pragma unroll
  for (int ks = 0; ks < 4; ++ks) {
    kfA[ks] = *(const bf16x8*)(kBase[0] + ks * 16);
    kfA[ks + 4] = *(const bf16x8*)(kBase[1] + ks * 16);
  }

#define FLASH_ITER(KC, KN, T)                                                    \
  {                                                                              \
    int kvN = ((T) + 1 < 32) ? ((T) + 1) * 64 : 0;                               \
    _Pragma("unroll") for (int ks = 0; ks < 4; ++ks) {                           \
      KN[ks] = *(const bf16x8*)(kBase[0] + (size_t)kvN * 64 + ks * 16);          \
      KN[ks + 4] = *(const bf16x8*)(kBase[1] + (size_t)kvN * 64 + ks * 16);      \
    }                                                                            \
    __builtin_amdgcn_sched_barrier(0);                                           \
    int kv0 = (T) * 64;                                                          \
    f32x16 s0, s1;                                                               \
    _Pragma("unroll") for (int i = 0; i < 16; ++i) { s0[i] = negC; s1[i] = negC; } \
    _Pragma("unroll") for (int ks = 0; ks < 4; ++ks) {                           \
      s0 = MFMA32(KC[ks], qB[ks], s0);                                           \
      s1 = MFMA32(KC[ks + 4], qB[ks], s1);                                       \
    }                                                                            \
    _Pragma("unroll") for (int ks = 0; ks < 4; ++ks) {                           \
      vf[ks] = *(const bf16x8*)(vBase[0] + kv0 + ks * 16);                       \
      vf[ks + 4] = *(const bf16x8*)(vBase[1] + kv0 + ks * 16);                   \
    }                                                                            \
    __builtin_amdgcn_sched_barrier(0);                                           \
    _Pragma("unroll") for (int i = 0; i < 16; ++i) {                             \
      float e0 = __expf(s0[i]);                                                  \
      float e1 = __expf(s1[i]);                                                  \
      lsum += e0 + e1;                                                           \
      s0[i] = e0; s1[i] = e1;                                                    \
    }                                                                            \
    bf16x8 pa[4];                                                                \
    {                                                                            \
      u32 c0 = cvtpk(s0[0], s0[1]),  c1 = cvtpk(s0[2], s0[3]);                   \
      u32 c2 = cvtpk(s0[4], s0[5]),  c3 = cvtpk(s0[6], s0[7]);                   \
      u32 c4 = cvtpk(s0[8], s0[9]),  c5 = cvtpk(s0[10], s0[11]);                 \
      u32 c6 = cvtpk(s0[12], s0[13]), c7 = cvtpk(s0[14], s0[15]);                \
      plswap(c0, c2); plswap(c1, c3); plswap(c4, c6); plswap(c5, c7);            \
      pa[0] = asbf((u32x4){c0, c1, c2, c3});                                     \
      pa[1] = asbf((u32x4){c4, c5, c6, c7});                                     \
      u32 d0 = cvtpk(s1[0], s1[1]),  d1 = cvtpk(s1[2], s1[3]);                   \
      u32 d2 = cvtpk(s1[4], s1[5]),  d3 = cvtpk(s1[6], s1[7]);                   \
      u32 d4 = cvtpk(s1[8], s1[9]),  d5 = cvtpk(s1[10], s1[11]);                 \
      u32 d6 = cvtpk(s1[12], s1[13]), d7 = cvtpk(s1[14], s1[15]);                \
      plswap(d0, d2); plswap(d1, d3); plswap(d4, d6); plswap(d5, d7);            \
      pa[2] = asbf((u32x4){d0, d1, d2, d3});                                     \
      pa[3] = asbf((u32x4){d4, d5, d6, d7});                                     \
    }                                                                            \
    _Pragma("unroll") for (int ks = 0; ks < 4; ++ks) {                           \
      o0 = MFMA32(pa[ks], vf[ks], o0);                                           \
      o1 = MFMA32(pa[ks], vf[ks + 4], o1);                                       \
    }                                                                            \
  }

#pragma unroll 1
  for (int t = 0; t < 32; t += 2) {
    FLASH_ITER(kfA, kfB, t);
    FLASH_ITER(kfB, kfA, t + 1);
  }
#undef FLASH_ITER

  // combine l across lane halves; redistribute per-q 1/l via LDS
  float ltot = lsum + __shfl_xor(lsum, 32, 64);
  if (h == 0) l_s[wave][r31] = 1.0f / ltot;
  __syncthreads();

#pragma unroll
  for (int r = 0; r < 16; ++r) {
    int cr = (r & 3) + ((r >> 2) << 3) + (h << 2);
    int qr = qw + cr;
    float li = l_s[wave][cr];
    size_t base = ((size_t)(b * 2048 + qr)) * 1024 + hd * 64;
    AO[base + r31] = f2bf(o0[r] * li);
    AO[base + 32 + r31] = f2bf(o1[r] * li);
  }
}

// ---------------- host ----------------
extern "C" void kernel_launch(void* const* d_in, const int* in_sizes, int n_in,
                              void* d_out, int out_size, void* d_ws, size_t ws_size,
                              hipStream_t stream) {
  const float* x = (const float*)d_in[0];
  const float* w_qkv = (const float*)d_in[1];
  const float* w_out = (const float*)d_in[2];
  const float* b_out = (const float*)d_in[3];
  const float* logit_scale = (const float*)d_in[4];

  char* ws = (char*)d_ws;
  u16* Xbf   = (u16*)(ws);                   // 8 MB  [4096][1024]
  u16* Wqkvt = (u16*)(ws + (8ll << 20));     // 6 MB  [3072][1024]
  u16* Woutt = (u16*)(ws + (14ll << 20));    // 2 MB  [1024][1024]
  u16* QKV   = (u16*)(ws + (16ll << 20));    // 24 MB [4096][3072]
  u16* Qn    = (u16*)(ws + (40ll << 20));    // 8 MB  [2][16][2048][64]
  u16* Kn    = (u16*)(ws + (48ll << 20));    // 8 MB
  u16* Vt    = (u16*)(ws + (56ll << 20));    // 8 MB  [2][16][64][2048]
  u16* AO    = Xbf;                          // reuse x-bf16 region [4096][1024]
  float* out = (float*)d_out;

  k_cvt_bf16<<<2048, 256, 0, stream>>>(x, Xbf, 524288);
  k_transpose_bf16<<<dim3(48, 16), 256, 0, stream>>>(w_qkv, Wqkvt, 1024, 3072);
  k_transpose_bf16<<<dim3(16, 16), 256, 0, stream>>>(w_out, Woutt, 1024, 1024);
  k_gemm_bt<true, false><<<768, 256, 0, stream>>>(Xbf, Wqkvt, QKV, nullptr,
                                                  4096, 3072, 1024, 24);
  k_repack<<<dim3(32, 16, 2), 256, 0, stream>>>(QKV, logit_scale, Qn, Kn, Vt);
  k_flash<<<dim3(32, 16), 256, 0, stream>>>(Qn, Kn, Vt, logit_scale, AO);
  k_gemm_bt<false, true><<<256, 256, 0, stream>>>(AO, Woutt, out, b_out,
                                                  4096, 1024, 1024, 8);
}

// Round 7
// 150.770 us; speedup vs baseline: 1.6227x; 1.4138x over previous
//
#include <hip/hip_runtime.h>

typedef __attribute__((ext_vector_type(8))) short bf16x8;
typedef __attribute__((ext_vector_type(4))) float f32x4;
typedef __attribute__((ext_vector_type(16))) float f32x16;
typedef unsigned short u16;
typedef unsigned int u32;
typedef __attribute__((ext_vector_type(4))) unsigned int u32x4;

#define DEV static __device__ __forceinline__

DEV u16 f2bf(float f) {
  u32 u = __float_as_uint(f);
  u += 0x7FFFu + ((u >> 16) & 1u);
  return (u16)(u >> 16);
}
DEV float bf2f(u16 h) { return __uint_as_float(((u32)h) << 16); }

DEV void gload16(const void* g, void* l) {
  __builtin_amdgcn_global_load_lds((const __attribute__((address_space(1))) void*)g,
                                   (__attribute__((address_space(3))) void*)l, 16, 0, 0);
}

#define MFMA16(a, b, c) __builtin_amdgcn_mfma_f32_16x16x32_bf16((a), (b), (c), 0, 0, 0)
#define MFMA32(a, b, c) __builtin_amdgcn_mfma_f32_32x32x16_bf16((a), (b), (c), 0, 0, 0)

DEV u32 cvtpk(float lo, float hi) {
  u32 r;
  asm("v_cvt_pk_bf16_f32 %0, %1, %2" : "=v"(r) : "v"(lo), "v"(hi));
  return r;
}
DEV void plswap(u32& a, u32& b) {
  asm volatile("v_permlane32_swap_b32 %0, %1" : "+v"(a), "+v"(b));
}
DEV bf16x8 asbf(u32x4 v) {
  union { u32x4 u; bf16x8 b; } x;
  x.u = v;
  return x.b;
}

// raw barrier with compiler fences: no implicit vmcnt drain (unlike __syncthreads)
DEV void rawbar() {
  __builtin_amdgcn_sched_barrier(0);
  asm volatile("" ::: "memory");
  __builtin_amdgcn_s_barrier();
  asm volatile("" ::: "memory");
  __builtin_amdgcn_sched_barrier(0);
}
#define VMCNT4() asm volatile("s_waitcnt vmcnt(4)" ::: "memory")
#define VMCNT0() asm volatile("s_waitcnt vmcnt(0)" ::: "memory")

// ---------------- fp32 -> bf16 convert (x) ----------------
__global__ __launch_bounds__(256) void k_cvt_bf16(const float* __restrict__ in,
                                                  u16* __restrict__ out, int n8) {
  int i = blockIdx.x * 256 + threadIdx.x;
  if (i >= n8) return;
  const f32x4* p = (const f32x4*)(in + (size_t)i * 8);
  f32x4 a = p[0], b = p[1];
  bf16x8 o;
  o[0] = (short)f2bf(a[0]); o[1] = (short)f2bf(a[1]);
  o[2] = (short)f2bf(a[2]); o[3] = (short)f2bf(a[3]);
  o[4] = (short)f2bf(b[0]); o[5] = (short)f2bf(b[1]);
  o[6] = (short)f2bf(b[2]); o[7] = (short)f2bf(b[3]);
  *(bf16x8*)(out + (size_t)i * 8) = o;
}

// ---------------- fp32 [rows][cols] -> bf16 [cols][rows] ----------------
__global__ __launch_bounds__(256) void k_transpose_bf16(const float* __restrict__ src,
                                                        u16* __restrict__ dst,
                                                        int rows, int cols) {
  __shared__ u16 lds[64][72];
  int t = threadIdx.x;
  int r0 = blockIdx.y * 64, c0 = blockIdx.x * 64;
  int r = t >> 2, cq = (t & 3) << 4;
  const float* s = src + (size_t)(r0 + r) * cols + c0 + cq;
#pragma unroll
  for (int i = 0; i < 16; i += 4) {
    f32x4 v = *(const f32x4*)(s + i);
    lds[r][cq + i + 0] = f2bf(v[0]);
    lds[r][cq + i + 1] = f2bf(v[1]);
    lds[r][cq + i + 2] = f2bf(v[2]);
    lds[r][cq + i + 3] = f2bf(v[3]);
  }
  __syncthreads();
  int c = t >> 2, rq = (t & 3) << 4;
  bf16x8 o0, o1;
#pragma unroll
  for (int i = 0; i < 8; ++i) o0[i] = (short)lds[rq + i][c];
#pragma unroll
  for (int i = 0; i < 8; ++i) o1[i] = (short)lds[rq + 8 + i][c];
  u16* d = dst + (size_t)(c0 + c) * rows + r0 + rq;
  *(bf16x8*)d = o0;
  *(bf16x8*)(d + 8) = o1;
}

// ---------------- bf16 GEMM: C[M][N] = A[M][K] * Bt[N][K]^T ----------------
// 1D grid with bijective XCD swizzle (nwg % 8 == 0): wg = (orig&7)*(nwg/8) + orig/8.
template <bool OUT_BF16, bool HAS_BIAS>
__global__ __launch_bounds__(256) void k_gemm_bt(const u16* __restrict__ A,
                                                 const u16* __restrict__ Bt,
                                                 void* __restrict__ Cout,
                                                 const float* __restrict__ bias,
                                                 int M, int N, int K, int nbx) {
  __shared__ __align__(16) u16 lsA[128 * 32];
  __shared__ __align__(16) u16 lsB[128 * 32];
  int tid = threadIdx.x;
  int lane = tid & 63, wave = tid >> 6;
  int wr = (wave >> 1) * 64, wc = (wave & 1) * 64;
  int nwg = gridDim.x;
  int orig = blockIdx.x;
  int wg = (orig & 7) * (nwg >> 3) + (orig >> 3);
  int bm = (wg / nbx) * 128, bn = (wg % nbx) * 128;

  f32x4 acc[4][4] = {};

  const u16* aSrc[2]; u16* aDst[2];
  const u16* bSrc[2]; u16* bDst[2];
#pragma unroll
  for (int j = 0; j < 2; ++j) {
    int s = wave * 128 + j * 64 + lane;
    int row = s >> 2, chunk = s & 3;
    int g = chunk ^ ((row >> 1) & 3);
    aSrc[j] = A + (size_t)(bm + row) * K + g * 8;
    bSrc[j] = Bt + (size_t)(bn + row) * K + g * 8;
    aDst[j] = &lsA[(wave * 128 + j * 64) * 8];
    bDst[j] = &lsB[(wave * 128 + j * 64) * 8];
  }

  for (int k0 = 0; k0 < K; k0 += 32) {
    __syncthreads();
    gload16(aSrc[0] + k0, aDst[0]);
    gload16(aSrc[1] + k0, aDst[1]);
    gload16(bSrc[0] + k0, bDst[0]);
    gload16(bSrc[1] + k0, bDst[1]);
    __syncthreads();
    bf16x8 af[4], bfr[4];
#pragma unroll
    for (int m = 0; m < 4; ++m) {
      int r = wr + m * 16 + (lane & 15);
      int p = (lane >> 4) ^ ((r >> 1) & 3);
      af[m] = *(const bf16x8*)&lsA[r * 32 + p * 8];
    }
#pragma unroll
    for (int n = 0; n < 4; ++n) {
      int r = wc + n * 16 + (lane & 15);
      int p = (lane >> 4) ^ ((r >> 1) & 3);
      bfr[n] = *(const bf16x8*)&lsB[r * 32 + p * 8];
    }
#pragma unroll
    for (int m = 0; m < 4; ++m)
#pragma unroll
      for (int n = 0; n < 4; ++n)
        acc[m][n] = MFMA16(af[m], bfr[n], acc[m][n]);
  }

#pragma unroll
  for (int m = 0; m < 4; ++m) {
    int row = bm + wr + m * 16 + ((lane >> 4) << 2);
#pragma unroll
    for (int n = 0; n < 4; ++n) {
      int col = bn + wc + n * 16 + (lane & 15);
#pragma unroll
      for (int j = 0; j < 4; ++j) {
        if (OUT_BF16) {
          ((u16*)Cout)[(size_t)(row + j) * N + col] = f2bf(acc[m][n][j]);
        } else {
          float bb = HAS_BIAS ? bias[col] : 0.f;
          ((float*)Cout)[(size_t)(row + j) * N + col] = acc[m][n][j] + bb;
        }
      }
    }
  }
}

// ---------------- repack: normalize q,k (fold scale into q), transpose v ----------------
__global__ __launch_bounds__(256) void k_repack(const u16* __restrict__ QKV,
                                                const float* __restrict__ logit_scale,
                                                u16* __restrict__ Qn, u16* __restrict__ Kn,
                                                u16* __restrict__ Vt) {
  int nt = blockIdx.x;  // 0..31 (64-row tile)
  int h = blockIdx.y;   // 0..15
  int b = blockIdx.z;   // 0..1
  int tid = threadIdx.x;
  int lane = tid & 63, wave = tid >> 6;
  int bh = b * 16 + h;
  float scale = __expf(fminf(logit_scale[h], 4.6051701859880914f));

#pragma unroll 1
  for (int i = 0; i < 16; ++i) {
    int n = nt * 64 + wave * 16 + i;
    size_t off = ((size_t)(b * 2048 + n)) * 3072 + h * 64 + lane;
    float q = bf2f(QKV[off]);
    float k = bf2f(QKV[off + 1024]);
    float sq = q * q, sk = k * k;
#pragma unroll
    for (int d = 1; d < 64; d <<= 1) {
      sq += __shfl_xor(sq, d, 64);
      sk += __shfl_xor(sk, d, 64);
    }
    float rq = scale / fmaxf(sqrtf(sq), 1e-12f);
    float rk = 1.0f / fmaxf(sqrtf(sk), 1e-12f);
    size_t o2 = ((size_t)bh * 2048 + n) * 64 + lane;
    Qn[o2] = f2bf(q * rq);
    Kn[o2] = f2bf(k * rk);
  }

  // V transpose via LDS
  __shared__ u16 lds[64][72];
  int r = tid >> 2, cq = (tid & 3) << 4;
  size_t voff = ((size_t)(b * 2048 + nt * 64 + r)) * 3072 + 2048 + h * 64 + cq;
  *(bf16x8*)&lds[r][cq] = *(const bf16x8*)&QKV[voff];
  *(bf16x8*)&lds[r][cq + 8] = *(const bf16x8*)&QKV[voff + 8];
  __syncthreads();
  int d = tid >> 2, nq = (tid & 3) << 4;
  bf16x8 o0, o1;
#pragma unroll
  for (int i = 0; i < 8; ++i) o0[i] = (short)lds[nq + i][d];
#pragma unroll
  for (int i = 0; i < 8; ++i) o1[i] = (short)lds[nq + 8 + i][d];
  u16* vd = Vt + ((size_t)bh * 64 + d) * 2048 + nt * 64 + nq;
  *(bf16x8*)vd = o0;
  *(bf16x8*)(vd + 8) = o1;
}

// ---------------- flash attention (LDS double-buffer, counted-vmcnt, raw barriers) ----------------
// R4 structure + T4: issue next tile's 4 global_load_lds FIRST, then s_waitcnt vmcnt(4)
// (waits only current tile's staging; next tile's loads stay in flight across the barrier),
// raw s_barrier (no drain), compute, raw s_barrier (read-protection before overwrite).
// T5 setprio(1) around MFMA clusters. grid (bh=32, qblk=16, split=2), blockIdx.x = bh
// keeps each head's blocks on one XCD (K/V L2-resident, R4: FETCH 12MB).
__global__ __launch_bounds__(256, 2) void k_flash(const u16* __restrict__ Qn,
                                                  const u16* __restrict__ Kn,
                                                  const u16* __restrict__ Vt,
                                                  const float* __restrict__ logit_scale,
                                                  u16* __restrict__ Op,
                                                  float* __restrict__ Lp) {
  __shared__ __align__(16) u16 lsK[2][64 * 64];
  __shared__ __align__(16) u16 lsV[2][64 * 64];
  __shared__ float l_s[4][32];
  int tid = threadIdx.x, lane = tid & 63, wave = tid >> 6;
  int r31 = lane & 31, h = lane >> 5;
  int bh = blockIdx.x, hd = bh & 15;
  int qw = blockIdx.y * 128 + wave * 32;
  int sp = blockIdx.z;
  const u16* Q = Qn + (size_t)bh * 2048 * 64;
  const u16* Kb = Kn + (size_t)bh * 2048 * 64 + (size_t)sp * 1024 * 64;
  const u16* Vb = Vt + (size_t)bh * 64 * 2048 + (size_t)sp * 1024;

  float negC = -__expf(fminf(logit_scale[hd], 4.6051701859880914f));

  // Q B-fragments: col=lane&31=q, k(d) = 16*ks + 8*h + e
  bf16x8 qB[4];
#pragma unroll
  for (int ks = 0; ks < 4; ++ks)
    qB[ks] = *(const bf16x8*)&Q[(size_t)(qw + r31) * 64 + ks * 16 + h * 8];

  // staging offsets (pre-swizzled global source, linear LDS dest)
  size_t kGO[2], vGO[2];
  int lOff[2];
#pragma unroll
  for (int j = 0; j < 2; ++j) {
    int s = j * 256 + tid;
    int row = s >> 3, ch = s & 7, g = ch ^ (row & 7);
    kGO[j] = (size_t)row * 64 + g * 8;
    vGO[j] = (size_t)row * 2048 + g * 8;
    lOff[j] = s * 8;
  }

  // LDS read offsets (swizzled): rows a*32+r31, chunk (2*ks+h) ^ (r31&7)
  int off[2][4];
#pragma unroll
  for (int a = 0; a < 2; ++a)
#pragma unroll
    for (int ks = 0; ks < 4; ++ks)
      off[a][ks] = (a * 32 + r31) * 64 + ((((ks << 1) | h) ^ (r31 & 7)) << 3);

  f32x16 o0, o1;
#pragma unroll
  for (int i = 0; i < 16; ++i) { o0[i] = 0.f; o1[i] = 0.f; }
  float lsum = 0.f;

#define STAGE(dstbuf, kvt)                                          \
  {                                                                 \
    size_t kv0 = (size_t)(kvt) * 64;                                \
    gload16(Kb + kv0 * 64 + kGO[0], &lsK[dstbuf][lOff[0]]);         \
    gload16(Kb + kv0 * 64 + kGO[1], &lsK[dstbuf][lOff[1]]);         \
    gload16(Vb + kv0 + vGO[0], &lsV[dstbuf][lOff[0]]);              \
    gload16(Vb + kv0 + vGO[1], &lsV[dstbuf][lOff[1]]);              \
  }

  // prologue: stage tile 0 (no wait; first iteration's VMCNT covers it)
  STAGE(0, 0);

#pragma unroll 1
  for (int t = 0; t < 16; ++t) {
    int cur = t & 1;
    if (t < 15) {
      STAGE(cur ^ 1, t + 1);  // next tile's 4 loads: stay in flight across barrier
      VMCNT4();               // wait only the 4 older loads (tile t's staging)
    } else {
      VMCNT0();
    }
    rawbar();                 // buf[cur] ready for all waves
    const u16* Kl = lsK[cur];
    const u16* Vl = lsV[cur];

    // S^T = K Q^T - scale   (rows kv, cols q)
    f32x16 s0, s1;
#pragma unroll
    for (int i = 0; i < 16; ++i) { s0[i] = negC; s1[i] = negC; }
    bf16x8 k0f[4], k1f[4];
#pragma unroll
    for (int ks = 0; ks < 4; ++ks) {
      k0f[ks] = *(const bf16x8*)&Kl[off[0][ks]];
      k1f[ks] = *(const bf16x8*)&Kl[off[1][ks]];
    }
    __builtin_amdgcn_s_setprio(1);
#pragma unroll
    for (int ks = 0; ks < 4; ++ks) {
      s0 = MFMA32(k0f[ks], qB[ks], s0);
      s1 = MFMA32(k1f[ks], qB[ks], s1);
    }
    __builtin_amdgcn_s_setprio(0);

    // V fragments (LDS)
    bf16x8 v0f[4], v1f[4];
#pragma unroll
    for (int ks = 0; ks < 4; ++ks) {
      v0f[ks] = *(const bf16x8*)&Vl[off[0][ks]];
      v1f[ks] = *(const bf16x8*)&Vl[off[1][ks]];
    }

    // P = exp(S - scale), lane-local l accumulation (no max, no shuffles)
#pragma unroll
    for (int i = 0; i < 16; ++i) {
      float e0 = __expf(s0[i]);
      float e1 = __expf(s1[i]);
      lsum += e0 + e1;
      s0[i] = e0; s1[i] = e1;
    }

    // pack P rows into PV A-fragments: cvt_pk pairs + permlane32 half-swap
    bf16x8 pa[4];
    {
      u32 c0 = cvtpk(s0[0], s0[1]),  c1 = cvtpk(s0[2], s0[3]);
      u32 c2 = cvtpk(s0[4], s0[5]),  c3 = cvtpk(s0[6], s0[7]);
      u32 c4 = cvtpk(s0[8], s0[9]),  c5 = cvtpk(s0[10], s0[11]);
      u32 c6 = cvtpk(s0[12], s0[13]), c7 = cvtpk(s0[14], s0[15]);
      plswap(c0, c2); plswap(c1, c3); plswap(c4, c6); plswap(c5, c7);
      pa[0] = asbf((u32x4){c0, c1, c2, c3});
      pa[1] = asbf((u32x4){c4, c5, c6, c7});
      u32 d0 = cvtpk(s1[0], s1[1]),  d1 = cvtpk(s1[2], s1[3]);
      u32 d2 = cvtpk(s1[4], s1[5]),  d3 = cvtpk(s1[6], s1[7]);
      u32 d4 = cvtpk(s1[8], s1[9]),  d5 = cvtpk(s1[10], s1[11]);
      u32 d6 = cvtpk(s1[12], s1[13]), d7 = cvtpk(s1[14], s1[15]);
      plswap(d0, d2); plswap(d1, d3); plswap(d4, d6); plswap(d5, d7);
      pa[2] = asbf((u32x4){d0, d1, d2, d3});
      pa[3] = asbf((u32x4){d4, d5, d6, d7});
    }

    // O += P V
    __builtin_amdgcn_s_setprio(1);
#pragma unroll
    for (int ks = 0; ks < 4; ++ks) {
      o0 = MFMA32(pa[ks], v0f[ks], o0);
      o1 = MFMA32(pa[ks], v1f[ks], o1);
    }
    __builtin_amdgcn_s_setprio(0);

    rawbar();                 // all waves done reading buf[cur]; next STAGE may overwrite
  }
#undef STAGE

  // combine l across lane halves; stash per-split l; redistribute 1/l via LDS
  float ltot = lsum + __shfl_xor(lsum, 32, 64);
  if (h == 0) {
    l_s[wave][r31] = 1.0f / ltot;
    Lp[((size_t)sp * 32 + bh) * 2048 + qw + r31] = ltot;
  }
  __syncthreads();

#pragma unroll
  for (int r = 0; r < 16; ++r) {
    int cr = (r & 3) + ((r >> 2) << 3) + (h << 2);
    int qr = qw + cr;
    float li = l_s[wave][cr];
    size_t base = (((size_t)sp * 32 + bh) * 2048 + qr) * 64;
    Op[base + r31] = f2bf(o0[r] * li);
    Op[base + 32 + r31] = f2bf(o1[r] * li);
  }
}

// ---------------- combine split-KV partials -> AO[b*2048+n][h*64+d] ----------------
__global__ __launch_bounds__(256) void k_combine(const u16* __restrict__ Op,
                                                 const float* __restrict__ Lp,
                                                 u16* __restrict__ AO) {
  int idx = blockIdx.x * 256 + threadIdx.x;  // 524288 groups of 8
  int row = idx >> 3;                        // bh*2048 + n
  int d0 = (idx & 7) << 3;
  float l1 = Lp[row], l2 = Lp[65536 + row];
  float inv = 1.0f / (l1 + l2);
  float w1 = l1 * inv, w2 = l2 * inv;
  bf16x8 a = *(const bf16x8*)&Op[(size_t)row * 64 + d0];
  bf16x8 b = *(const bf16x8*)&Op[4194304 + (size_t)row * 64 + d0];
  int bh = row >> 11, n = row & 2047;
  int bb = bh >> 4, hd = bh & 15;
  bf16x8 o;
#pragma unroll
  for (int e = 0; e < 8; ++e)
    o[e] = (short)f2bf(w1 * bf2f(a[e]) + w2 * bf2f(b[e]));
  *(bf16x8*)&AO[((size_t)(bb * 2048 + n)) * 1024 + hd * 64 + d0] = o;
}

// ---------------- host ----------------
extern "C" void kernel_launch(void* const* d_in, const int* in_sizes, int n_in,
                              void* d_out, int out_size, void* d_ws, size_t ws_size,
                              hipStream_t stream) {
  const float* x = (const float*)d_in[0];
  const float* w_qkv = (const float*)d_in[1];
  const float* w_out = (const float*)d_in[2];
  const float* b_out = (const float*)d_in[3];
  const float* logit_scale = (const float*)d_in[4];

  char* ws = (char*)d_ws;
  u16* Xbf   = (u16*)(ws);                   // 8 MB  [4096][1024]
  u16* Wqkvt = (u16*)(ws + (8ll << 20));     // 6 MB  [3072][1024] (reused as Lp after gemm1)
  u16* Woutt = (u16*)(ws + (14ll << 20));    // 2 MB  [1024][1024]
  u16* QKV   = (u16*)(ws + (16ll << 20));    // 24 MB [4096][3072] (reused as Op after repack)
  u16* Qn    = (u16*)(ws + (40ll << 20));    // 8 MB  [2][16][2048][64]
  u16* Kn    = (u16*)(ws + (48ll << 20));    // 8 MB
  u16* Vt    = (u16*)(ws + (56ll << 20));    // 8 MB  [2][16][64][2048]
  u16* Op    = QKV;                          // 16 MB [2][32][2048][64] bf16
  float* Lp  = (float*)Wqkvt;                // 0.5 MB [2][32][2048] f32
  u16* AO    = Xbf;                          // reuse x-bf16 region [4096][1024]
  float* out = (float*)d_out;

  k_cvt_bf16<<<2048, 256, 0, stream>>>(x, Xbf, 524288);
  k_transpose_bf16<<<dim3(48, 16), 256, 0, stream>>>(w_qkv, Wqkvt, 1024, 3072);
  k_transpose_bf16<<<dim3(16, 16), 256, 0, stream>>>(w_out, Woutt, 1024, 1024);
  k_gemm_bt<true, false><<<768, 256, 0, stream>>>(Xbf, Wqkvt, QKV, nullptr,
                                                  4096, 3072, 1024, 24);
  k_repack<<<dim3(32, 16, 2), 256, 0, stream>>>(QKV, logit_scale, Qn, Kn, Vt);
  k_flash<<<dim3(32, 16, 2), 256, 0, stream>>>(Qn, Kn, Vt, logit_scale, Op, Lp);
  k_combine<<<2048, 256, 0, stream>>>(Op, Lp, AO);
  k_gemm_bt<false, true><<<256, 256, 0, stream>>>(AO, Woutt, out, b_out,
                                                  4096, 1024, 1024, 8);
}